// Round 14
// baseline (112.954 us; speedup 1.0000x reference)
//
#include <hip/hip_runtime.h>
#include <math.h>

#define NCOL 32
#define DDIM 512
#define CATS 10
#define ROW_STRIDE (NCOL * DDIM)   /* 16384 floats between consecutive b rows */
#define NBODY 128                  /* row-stride between a block's rows       */
#define NITER 64                   /* rows per block: 8192/128                */

// ---- DPP reduce helpers: byte-identical to all passing rounds -------------
template <int CTRL, int ROW_MASK>
__device__ __forceinline__ float dpp_add(float v) {
    int t = __builtin_amdgcn_update_dpp(0, __float_as_int(v), CTRL, ROW_MASK, 0xf, false);
    return v + __int_as_float(t);
}
template <int CTRL, int ROW_MASK>
__device__ __forceinline__ float dpp_mov(float v) {
    int t = __builtin_amdgcn_update_dpp(0, __float_as_int(v), CTRL, ROW_MASK, 0xf, false);
    return __int_as_float(t);
}
__device__ __forceinline__ float wave_reduce_halves(float v) {
    v = dpp_add<0x111, 0xf>(v);
    v = dpp_add<0x112, 0xf>(v);
    v = dpp_add<0x114, 0xf>(v);
    v = dpp_add<0x118, 0xf>(v);
    v = dpp_add<0x142, 0xa>(v);
    return v;
}
__device__ __forceinline__ float wave_reduce_full(float v) {
    v = wave_reduce_halves(v);
    v = dpp_add<0x143, 0xc>(v);
    return v;
}

#define WAITVMN(n) asm volatile("s_waitcnt vmcnt(%0)" :: "i"(n) : "memory")
#define LGKM0()    asm volatile("s_waitcnt lgkmcnt(0)" ::: "memory")
#define SCHEDF()   __builtin_amdgcn_sched_barrier(0)
// raw barrier (no implicit vmcnt(0) drain, unlike __syncthreads)
#define BARRIER()  do { SCHEDF(); __builtin_amdgcn_s_barrier(); SCHEDF(); } while (0)

// each wave stages its OWN column (512 floats = 2 KiB = 2 chunks) of the row
#define ISSUE(row, slot) do {                                                  \
    const float* _g = x + (size_t)(row) * ROW_STRIDE + colbase;                \
    float* _l = &slab[slot][wv * 512];                                         \
    __builtin_amdgcn_global_load_lds(                                          \
        (const __attribute__((address_space(1))) unsigned int*)(_g + lane * 4),\
        (__attribute__((address_space(3))) unsigned int*)(_l), 16, 0, 0);      \
    __builtin_amdgcn_global_load_lds(                                          \
        (const __attribute__((address_space(1))) unsigned int*)                \
            (_g + 256 + lane * 4),                                             \
        (__attribute__((address_space(3))) unsigned int*)(_l + 256),           \
        16, 0, 0);                                                             \
} while (0)

// ---- half 0 (waves 0,2): num + cat ch 0..3, combine + store ---------------
#define BODY0(NW, DOISS) do {                                                  \
    if (DOISS) ISSUE(r + 3 * NBODY, (j + 3) & 3);                              \
    WAITVMN(NW);                                                               \
    BARRIER();                /* bar1: all 4 columns of row r are in LDS */    \
    const float* pb = &slab[j & 3][pl * 1024];                                 \
    float4 Ea = *(const float4*)(pb +   0 + 4 * lane);                         \
    float4 Eb = *(const float4*)(pb + 256 + 4 * lane);                         \
    float4 Oa = *(const float4*)(pb + 512 + 4 * lane);                         \
    float4 Ob = *(const float4*)(pb + 768 + 4 * lane);                         \
    float sn = Ea.x * w8[0];                                                   \
    sn = fmaf(Ea.y, w8[1], sn);                                                \
    sn = fmaf(Ea.z, w8[2], sn);                                                \
    sn = fmaf(Ea.w, w8[3], sn);                                                \
    sn = fmaf(Eb.x, w8[4], sn);                                                \
    sn = fmaf(Eb.y, w8[5], sn);                                                \
    sn = fmaf(Eb.z, w8[6], sn);                                                \
    sn = fmaf(Eb.w, w8[7], sn);                                                \
    sn = wave_reduce_full(sn);                                                 \
    double best = -1.0e300; int bi = 0;                                        \
    _Pragma("unroll")                                                          \
    for (int c = 0; c < 4; ++c) {                                              \
        float s = Oa.x * wc0[c];                                               \
        s = fmaf(Oa.y, wc0[ 4 + c], s);                                        \
        s = fmaf(Oa.z, wc0[ 8 + c], s);                                        \
        s = fmaf(Oa.w, wc0[12 + c], s);                                        \
        s = fmaf(Ob.x, wc0[16 + c], s);                                        \
        s = fmaf(Ob.y, wc0[20 + c], s);                                        \
        s = fmaf(Ob.z, wc0[24 + c], s);                                        \
        s = fmaf(Ob.w, wc0[28 + c], s);                                        \
        s = wave_reduce_halves(s);                                             \
        float slo = dpp_mov<0x143, 0xc>(s);                                    \
        double d = (double)s + (double)slo + biasd[c];                         \
        if (d > best) { best = d; bi = c; }                                    \
    }                                                                          \
    LGKM0(); SCHEDF();                                                         \
    BARRIER();                /* bar2: partner's (best,bi) is in mbox */       \
    double od = mbox_d[pl]; int oi = mbox_i[pl];                               \
    if (od > best) { best = od; bi = oi; }  /* higher chans must strictly win */\
    if (lane == 63) {                                                          \
        float2 o2 = make_float2(tanhf(sn + bias), (float)bi);                  \
        *(float2*)(out + (size_t)r * NCOL + 2 * p) = o2;                       \
    }                                                                          \
    r += NBODY;                                                                \
} while (0)

// ---- half 1 (waves 1,3): cat ch 4..9 -> mailbox ---------------------------
#define BODY1(NW, DOISS) do {                                                  \
    if (DOISS) ISSUE(r + 3 * NBODY, (j + 3) & 3);                              \
    WAITVMN(NW);                                                               \
    BARRIER();                /* bar1 */                                       \
    const float* pb = &slab[j & 3][pl * 1024];                                 \
    float4 Oa = *(const float4*)(pb + 512 + 4 * lane);                         \
    float4 Ob = *(const float4*)(pb + 768 + 4 * lane);                         \
    double best = -1.0e300; int bi = 4;                                        \
    _Pragma("unroll")                                                          \
    for (int ci = 0; ci < 6; ++ci) {                                           \
        float s = Oa.x * wc1[ci];                                              \
        s = fmaf(Oa.y, wc1[ 6 + ci], s);                                       \
        s = fmaf(Oa.z, wc1[12 + ci], s);                                       \
        s = fmaf(Oa.w, wc1[18 + ci], s);                                       \
        s = fmaf(Ob.x, wc1[24 + ci], s);                                       \
        s = fmaf(Ob.y, wc1[30 + ci], s);                                       \
        s = fmaf(Ob.z, wc1[36 + ci], s);                                       \
        s = fmaf(Ob.w, wc1[42 + ci], s);                                       \
        s = wave_reduce_halves(s);                                             \
        float slo = dpp_mov<0x143, 0xc>(s);                                    \
        double d = (double)s + (double)slo + biasd1[ci];                       \
        if (d > best) { best = d; bi = 4 + ci; }                               \
    }                                                                          \
    if (lane == 63) { mbox_d[pl] = best; mbox_i[pl] = bi; }                    \
    LGKM0(); SCHEDF();                                                         \
    BARRIER();                /* bar2 */                                       \
    r += NBODY;                                                                \
} while (0)

// Block = 4 waves / 2 pairs; wave wv stages column 4*oct+wv (block slab = 8KiB
// contiguous); channel-split cat halves occupancy at 16 waves/CU (was 12).
__global__ __launch_bounds__(256, 4) void split_pipe_kernel(
    const float* __restrict__ x,
    const float* __restrict__ Wn,
    const float* __restrict__ bn,
    const float* __restrict__ Wc,
    const float* __restrict__ bc,
    float* __restrict__ out)
{
    __shared__ __align__(16) float slab[4][2048];   // 4-slot ring, 32 KiB
    __shared__ double mbox_d[2];
    __shared__ int    mbox_i[2];

    const int lane = threadIdx.x & 63;
    const int wv   = threadIdx.x >> 6;                                // 0..3
    const int oct  = __builtin_amdgcn_readfirstlane(blockIdx.x & 7);  // 0..7
    const int body = __builtin_amdgcn_readfirstlane(blockIdx.x >> 3); // 0..127
    const int pl   = wv >> 1;                       // pair within block (0/1)
    const int half = wv & 1;                        // 0: num+ch0-3, 1: ch4-9
    const int p    = __builtin_amdgcn_readfirstlane(2 * oct + pl);
    const size_t colbase = (size_t)(4 * oct + wv) * DDIM;  // staged column

    int r = body;   // current row
    int j = 0;

    if (half == 0) {
        // num weights (per-lane slice of Wn[p]) — identical to passing rounds
        float w8[8];
        {
            float4 wa = *(const float4*)(Wn + p * DDIM + lane * 4);
            float4 wb = *(const float4*)(Wn + p * DDIM + 256 + lane * 4);
            w8[0]=wa.x; w8[1]=wa.y; w8[2]=wa.z; w8[3]=wa.w;
            w8[4]=wb.x; w8[5]=wb.y; w8[6]=wb.z; w8[7]=wb.w;
        }
        const float bias = __int_as_float(
            __builtin_amdgcn_readfirstlane(__float_as_int(bn[p])));

        // cat weights ch 0..3: wc0[dd*4+c] = Wc[(p*512 + d(dd))*10 + c]
        float wc0[32];
        {
            const float* reg0 = Wc + ((size_t)p * DDIM + 4 * lane) * CATS;
            const float* reg1 = Wc + ((size_t)p * DDIM + 256 + 4 * lane) * CATS;
            float tmp[40];
            #pragma unroll
            for (int k = 0; k < 10; ++k) {
                float4 t = *(const float4*)(reg0 + 4 * k);
                tmp[4*k]=t.x; tmp[4*k+1]=t.y; tmp[4*k+2]=t.z; tmp[4*k+3]=t.w;
            }
            #pragma unroll
            for (int dd = 0; dd < 4; ++dd)
                #pragma unroll
                for (int c = 0; c < 4; ++c) wc0[dd*4+c] = tmp[dd*10+c];
            #pragma unroll
            for (int k = 0; k < 10; ++k) {
                float4 t = *(const float4*)(reg1 + 4 * k);
                tmp[4*k]=t.x; tmp[4*k+1]=t.y; tmp[4*k+2]=t.z; tmp[4*k+3]=t.w;
            }
            #pragma unroll
            for (int dd = 0; dd < 4; ++dd)
                #pragma unroll
                for (int c = 0; c < 4; ++c) wc0[16+dd*4+c] = tmp[dd*10+c];
        }
        double biasd[4];
        #pragma unroll
        for (int c = 0; c < 4; ++c)
            biasd[c] = (double)__int_as_float(
                __builtin_amdgcn_readfirstlane(__float_as_int(bc[p * CATS + c])));

        ISSUE(body,             0);
        ISSUE(body + NBODY,     1);
        ISSUE(body + 2 * NBODY, 2);

        // vmcnt: j=0 exact 6; j=1,2 true 7,8 (6 = safe); steady 9; tails 7,5,3
        #pragma unroll 1
        for (; j < 3; ++j)  BODY0(6, true);
        #pragma unroll 1
        for (; j <= 60; ++j) BODY0(9, true);
        BODY0(7, false); ++j;
        BODY0(5, false); ++j;
        BODY0(3, false);
    } else {
        // cat weights ch 4..9: wc1[dd*6+ci] = Wc[(p*512 + d(dd))*10 + 4+ci]
        float wc1[48];
        {
            const float* reg0 = Wc + ((size_t)p * DDIM + 4 * lane) * CATS;
            const float* reg1 = Wc + ((size_t)p * DDIM + 256 + 4 * lane) * CATS;
            float tmp[40];
            #pragma unroll
            for (int k = 0; k < 10; ++k) {
                float4 t = *(const float4*)(reg0 + 4 * k);
                tmp[4*k]=t.x; tmp[4*k+1]=t.y; tmp[4*k+2]=t.z; tmp[4*k+3]=t.w;
            }
            #pragma unroll
            for (int dd = 0; dd < 4; ++dd)
                #pragma unroll
                for (int ci = 0; ci < 6; ++ci) wc1[dd*6+ci] = tmp[dd*10+4+ci];
            #pragma unroll
            for (int k = 0; k < 10; ++k) {
                float4 t = *(const float4*)(reg1 + 4 * k);
                tmp[4*k]=t.x; tmp[4*k+1]=t.y; tmp[4*k+2]=t.z; tmp[4*k+3]=t.w;
            }
            #pragma unroll
            for (int dd = 0; dd < 4; ++dd)
                #pragma unroll
                for (int ci = 0; ci < 6; ++ci) wc1[24+dd*6+ci] = tmp[dd*10+4+ci];
        }
        double biasd1[6];
        #pragma unroll
        for (int ci = 0; ci < 6; ++ci)
            biasd1[ci] = (double)__int_as_float(
                __builtin_amdgcn_readfirstlane(
                    __float_as_int(bc[p * CATS + 4 + ci])));

        ISSUE(body,             0);
        ISSUE(body + NBODY,     1);
        ISSUE(body + 2 * NBODY, 2);

        // vmcnt: 6 constant through j=60 (no stores); tails 4,2,0
        #pragma unroll 1
        for (; j <= 60; ++j) BODY1(6, true);
        BODY1(4, false); ++j;
        BODY1(2, false); ++j;
        BODY1(0, false);
    }
}

extern "C" void kernel_launch(void* const* d_in, const int* in_sizes, int n_in,
                              void* d_out, int out_size, void* d_ws, size_t ws_size,
                              hipStream_t stream) {
    const float* x  = (const float*)d_in[0];
    const float* Wn = (const float*)d_in[1];
    const float* bn = (const float*)d_in[2];
    const float* Wc = (const float*)d_in[3];
    const float* bc = (const float*)d_in[4];
    float* out = (float*)d_out;

    // 1024 blocks = 128 bodies x 8 octs; exactly 4 blocks/CU co-resident
    // (16 waves/CU). 8 consecutive blocks cover one full 64 KiB row.
    hipLaunchKernelGGL(split_pipe_kernel, dim3(1024), dim3(256), 0, stream,
                       x, Wn, bn, Wc, bc, out);
}